// Round 8
// baseline (645.884 us; speedup 1.0000x reference)
//
#include <hip/hip_runtime.h>
#include <cstddef>
#include <cstdint>

// x (32,64,64,16) f32; W (16,16,448,448) f32; bias (16,16) f32.
// Kept bands per axis: {cA6, cD6, cD5, cD1} -> band blocks {0,1,2,6} of the full 7.
// X1 (reused in place as Z1): (a, u in [0,256), j in [0,64), ch 16) = 32 MB in d_ws.

#define X1_IDX(a,u,j,d) ((((size_t)(a)*256 + (u))*64 + (j))*16 + (d))

// ---------------- K1: SWT along axis 1 (i -> u bands), x -> X1 ----------------
// block 256 = q(4) x jl(16) x dq(4); grid (32 a, 4 jc). All global/LDS as float4.
__global__ __launch_bounds__(256, 2) void k_swt1(const float* __restrict__ x,
                                                 float* __restrict__ X1) {
  __shared__ float col[64 * 256];   // [i][jl*16 + d]  64 KB
  __shared__ float Ps[4 * 256];     // per-16-chunk partial sums
  const int t = threadIdx.x;
  const int q = t >> 6;
  const int cc = (t & 63) * 4;               // jl*16 + dq*4
  const int jl = (t & 63) >> 2, dq = t & 3;
  const int a = blockIdx.x, j = blockIdx.y * 16 + jl;
  const float4* xp4 = (const float4*)(x + ((size_t)a * 4096 + j) * 16 + dq * 4);
  float4 P = make_float4(0.f, 0.f, 0.f, 0.f);
#pragma unroll
  for (int r = 0; r < 16; ++r) {
    const int i = q * 16 + r;
    float4 v = xp4[(size_t)i * 256];          // stride per i = 1024 floats
    *(float4*)&col[i * 256 + cc] = v;
    P.x += v.x; P.y += v.y; P.z += v.z; P.w += v.w;
  }
  *(float4*)&Ps[q * 256 + cc] = P;
  __syncthreads();
  const float4 p0 = *(const float4*)&Ps[0 * 256 + cc];
  const float4 p1 = *(const float4*)&Ps[1 * 256 + cc];
  const float4 p2 = *(const float4*)&Ps[2 * 256 + cc];
  const float4 p3 = *(const float4*)&Ps[3 * 256 + cc];
  float4 cA;
  cA.x = (p0.x + p1.x + p2.x + p3.x) * 0.015625f;
  cA.y = (p0.y + p1.y + p2.y + p3.y) * 0.015625f;
  cA.z = (p0.z + p1.z + p2.z + p3.z) * 0.015625f;
  cA.w = (p0.w + p1.w + p2.w + p3.w) * 0.015625f;
  float4 w4 = *(const float4*)&Ps[q * 256 + cc];
  float4 w4b = *(const float4*)&Ps[((q + 1) & 3) * 256 + cc];
  float4 w5;
  w5.x = w4.x + w4b.x; w5.y = w4.y + w4b.y; w5.z = w4.z + w4b.z; w5.w = w4.w + w4b.w;
  float4* X1p = (float4*)(X1 + X1_IDX(a, 0, j, dq * 4));  // stride per u = 256 float4
  float4 c0 = *(const float4*)&col[(q * 16) * 256 + cc];
#pragma unroll
  for (int r = 0; r < 16; ++r) {
    const int u = q * 16 + r;
    const float4 c1 = *(const float4*)&col[((u + 1) & 63) * 256 + cc];
    const float4 c16 = *(const float4*)&col[((u + 16) & 63) * 256 + cc];
    const float4 c32 = *(const float4*)&col[((u + 32) & 63) * 256 + cc];
    float4 b1, b2v, b3;
    b1.x = w5.x * 0.03125f - cA.x; b1.y = w5.y * 0.03125f - cA.y;
    b1.z = w5.z * 0.03125f - cA.z; b1.w = w5.w * 0.03125f - cA.w;
    b2v.x = (w4.x - w4b.x) * 0.03125f; b2v.y = (w4.y - w4b.y) * 0.03125f;
    b2v.z = (w4.z - w4b.z) * 0.03125f; b2v.w = (w4.w - w4b.w) * 0.03125f;
    b3.x = (c0.x - c1.x) * 0.5f; b3.y = (c0.y - c1.y) * 0.5f;
    b3.z = (c0.z - c1.z) * 0.5f; b3.w = (c0.w - c1.w) * 0.5f;
    X1p[(size_t)u * 256] = cA;
    X1p[(size_t)(64 + u) * 256] = b1;
    X1p[(size_t)(128 + u) * 256] = b2v;
    X1p[(size_t)(192 + u) * 256] = b3;
    w4.x += c16.x - c0.x; w4.y += c16.y - c0.y; w4.z += c16.z - c0.z; w4.w += c16.w - c0.w;
    w4b.x += c32.x - c16.x; w4b.y += c32.y - c16.y; w4b.z += c32.z - c16.z; w4b.w += c32.w - c16.w;
    w5.x += c32.x - c0.x; w5.y += c32.y - c0.y; w5.z += c32.z - c0.z; w5.w += c32.w - c0.w;
    c0 = c1;
  }
}

// ---------------- Fused: axis-2 SWT -> register-tiled channel mix -> axis-2 iSWT ----------------
// 512 threads, APB=8, 1 block/CU (154 KB LDS).
// bid -> u = (bid&7)*32 + (bid>>5), ac = (bid>>3)&3 : each u-panel lives on ONE XCD.
#define TSA 4104                 // per-a stride (4096 + 8 skew)
#define TS(a,v,d) ((a) * TSA + (v) * 16 + (d))
#define WLS_E 324                // Wl e-stride (16*20 + 4 skew)
#define WLS_V 20                 // Wl v-stride (16 d + 4 pad, 16B aligned)

__global__ __launch_bounds__(512, 1) void k_fused(float* __restrict__ X1,
                                                  const float* __restrict__ W) {
  __shared__ float Ts[8 * TSA];       // 131,328 B
  __shared__ float Wl[16 * WLS_E];    //  20,736 B  [e][vl@20][d]
  __shared__ float Ps[8 * 4 * 16];    //   2,048 B
  const int t = threadIdx.x;
  const int bid = blockIdx.x;
  const int u = (bid & 7) * 32 + (bid >> 5);
  const int ac = (bid >> 3) & 3;
  const int a0 = ac * 8;
  const int ub = u >> 6;
  const int Brow = (ub == 3 ? 6 : ub) * 64 + (u & 63);

  const bool isLoader = (t >= 128 && t < 192);   // wave 2
  const int ldq = (t >> 4) & 3, lel = t & 15;    // loader (d-quad, e)
  float pw[4][16];                               // [jd][vl] W values in flight

  // issue W loads for vg=0 immediately (hide HBM latency under phase A)
  if (isLoader) {
#pragma unroll
    for (int jd = 0; jd < 4; ++jd) {
      const int d = ldq * 4 + jd;
      const float* wp = W + (size_t)(d * 16 + lel) * 200704 + (size_t)Brow * 448;
#pragma unroll
      for (int vq = 0; vq < 4; ++vq) {
        float4 v = *(const float4*)(wp + vq * 4);
        pw[jd][vq * 4 + 0] = v.x; pw[jd][vq * 4 + 1] = v.y;
        pw[jd][vq * 4 + 2] = v.z; pw[jd][vq * 4 + 3] = v.w;
      }
    }
  }

  // ---- Phase A: axis-2 SWT. thread = (a 8, q 4, d 16); 16 v per thread ----
  {
    const int aA = t >> 6, qA = (t >> 4) & 3, dA = t & 15;
    const float* xpA = X1 + X1_IDX(a0 + aA, u, qA * 16, dA);
    float P = 0.f;
#pragma unroll
    for (int r = 0; r < 16; ++r) {
      float v = xpA[r * 16];
      Ts[TS(aA, 192 + qA * 16 + r, dA)] = v;   // stage raw into band-3 area
      P += v;
    }
    Ps[(aA * 4 + qA) * 16 + dA] = P;
    __syncthreads();
    const float S = Ps[(aA * 4 + 0) * 16 + dA] + Ps[(aA * 4 + 1) * 16 + dA]
                  + Ps[(aA * 4 + 2) * 16 + dA] + Ps[(aA * 4 + 3) * 16 + dA];
    const float cA = S * 0.015625f;
    float w4 = Ps[(aA * 4 + qA) * 16 + dA];
    float w4b = Ps[(aA * 4 + ((qA + 1) & 3)) * 16 + dA];
    float w5 = w4 + w4b;
    float cd1[16];
    float c0 = Ts[TS(aA, 192 + qA * 16, dA)];
#pragma unroll
    for (int r = 0; r < 16; ++r) {
      const int v = qA * 16 + r;
      const float c1 = Ts[TS(aA, 192 + ((v + 1) & 63), dA)];
      const float c16 = Ts[TS(aA, 192 + ((v + 16) & 63), dA)];
      const float c32 = Ts[TS(aA, 192 + ((v + 32) & 63), dA)];
      Ts[TS(aA, v, dA)] = cA;                            // cA6
      Ts[TS(aA, 64 + v, dA)] = w5 * 0.03125f - cA;       // cD6
      Ts[TS(aA, 128 + v, dA)] = (w4 - w4b) * 0.03125f;   // cD5
      cd1[r] = (c0 - c1) * 0.5f;                         // cD1 (deferred)
      w4 += c16 - c0; w4b += c32 - c16; w5 += c32 - c0;
      c0 = c1;
    }
    __syncthreads();
#pragma unroll
    for (int r = 0; r < 16; ++r) Ts[TS(aA, 192 + qA * 16 + r, dA)] = cd1[r];
  }
  __syncthreads();
  if (isLoader) {   // write Wl for vg=0
#pragma unroll
    for (int vl = 0; vl < 16; ++vl) {
      float4 o = make_float4(pw[0][vl], pw[1][vl], pw[2][vl], pw[3][vl]);
      *(float4*)&Wl[lel * WLS_E + vl * WLS_V + ldq * 4] = o;
    }
  }
  __syncthreads();

  // ---- Phase B: y[a,v,e] = sum_d T[a,v,d] * W[d,e,Brow,C(v)], 4a x 4e register tile ----
  {
    const bool isCompute = (t < 128);   // waves 0,1
    const int at = t >> 6, et = (t >> 4) & 3, vlB = t & 15;
    for (int vg = 0; vg < 16; ++vg) {
      float4 tf[4][4], wf[4][4];
      float acc[4][4];
      if (isCompute) {
        const int v = vg * 16 + vlB;
#pragma unroll
        for (int ja = 0; ja < 4; ++ja)
#pragma unroll
          for (int dq = 0; dq < 4; ++dq)
            tf[ja][dq] = *(const float4*)&Ts[TS(at * 4 + ja, v, dq * 4)];
#pragma unroll
        for (int je = 0; je < 4; ++je)
#pragma unroll
          for (int dq = 0; dq < 4; ++dq)
            wf[je][dq] = *(const float4*)&Wl[(et * 4 + je) * WLS_E + vlB * WLS_V + dq * 4];
      }
      if (isLoader && vg < 15) {      // prefetch W for vg+1
        const int v2 = vg + 1, kb = v2 >> 2;
        const int Ccol = (kb == 3 ? 6 : kb) * 64 + (v2 & 3) * 16;
#pragma unroll
        for (int jd = 0; jd < 4; ++jd) {
          const int d = ldq * 4 + jd;
          const float* wp = W + (size_t)(d * 16 + lel) * 200704 + (size_t)Brow * 448 + Ccol;
#pragma unroll
          for (int vq = 0; vq < 4; ++vq) {
            float4 v = *(const float4*)(wp + vq * 4);
            pw[jd][vq * 4 + 0] = v.x; pw[jd][vq * 4 + 1] = v.y;
            pw[jd][vq * 4 + 2] = v.z; pw[jd][vq * 4 + 3] = v.w;
          }
        }
      }
      if (isCompute) {
#pragma unroll
        for (int ja = 0; ja < 4; ++ja)
#pragma unroll
          for (int je = 0; je < 4; ++je) {
            float s = 0.f;
#pragma unroll
            for (int dq = 0; dq < 4; ++dq) {
              s += tf[ja][dq].x * wf[je][dq].x;
              s += tf[ja][dq].y * wf[je][dq].y;
              s += tf[ja][dq].z * wf[je][dq].z;
              s += tf[ja][dq].w * wf[je][dq].w;
            }
            acc[ja][je] = s;
          }
      }
      __syncthreads();   // all Ts/Wl reads of this vg complete
      if (isCompute) {
        const int v = vg * 16 + vlB;
#pragma unroll
        for (int ja = 0; ja < 4; ++ja) {
          float4 o = make_float4(acc[ja][0], acc[ja][1], acc[ja][2], acc[ja][3]);
          *(float4*)&Ts[TS(at * 4 + ja, v, et * 4)] = o;   // in-place y
        }
      }
      if (isLoader && vg < 15) {
#pragma unroll
        for (int vl = 0; vl < 16; ++vl) {
          float4 o = make_float4(pw[0][vl], pw[1][vl], pw[2][vl], pw[3][vl]);
          *(float4*)&Wl[lel * WLS_E + vl * WLS_V + ldq * 4] = o;
        }
      }
      __syncthreads();   // y written, Wl(vg+1) ready
    }
  }

  // ---- Phase C: axis-2 iSWT. thread = (a 8, q 4, e 16); 16 i per thread ----
  {
    const int aC = t >> 6, qC = (t >> 4) & 3, eC = t & 15;
    float rg[16];
    // L6: bands 0,1 -> band0
#pragma unroll
    for (int r = 0; r < 16; ++r) {
      const int i = qC * 16 + r, i2 = (i - 32) & 63;
      rg[r] = 0.5f * (Ts[TS(aC, i, eC)] + Ts[TS(aC, 64 + i, eC)]
                    + Ts[TS(aC, i2, eC)] - Ts[TS(aC, 64 + i2, eC)]);
    }
    __syncthreads();
#pragma unroll
    for (int r = 0; r < 16; ++r) Ts[TS(aC, qC * 16 + r, eC)] = rg[r];
    __syncthreads();
    // L5: bands 0,2 -> band1
#pragma unroll
    for (int r = 0; r < 16; ++r) {
      const int i = qC * 16 + r, i2 = (i - 16) & 63;
      rg[r] = 0.5f * (Ts[TS(aC, i, eC)] + Ts[TS(aC, 128 + i, eC)]
                    + Ts[TS(aC, i2, eC)] - Ts[TS(aC, 128 + i2, eC)]);
    }
    __syncthreads();
#pragma unroll
    for (int r = 0; r < 16; ++r) Ts[TS(aC, 64 + qC * 16 + r, eC)] = rg[r];
    __syncthreads();
    // L4*L3*L2 composed 8-tap as incremental sliding sum: band1 -> band0
    {
      float s0 = 0.f, s1 = 0.f;
#pragma unroll
      for (int k = 0; k < 8; ++k) s0 += Ts[TS(aC, 64 + ((qC * 16 - 2 * k) & 63), eC)];
#pragma unroll
      for (int k = 0; k < 8; ++k) s1 += Ts[TS(aC, 64 + ((qC * 16 + 1 - 2 * k) & 63), eC)];
      rg[0] = s0 * 0.125f; rg[1] = s1 * 0.125f;
#pragma unroll
      for (int r = 2; r < 16; ++r) {
        const int i = qC * 16 + r;
        const float add = Ts[TS(aC, 64 + i, eC)] - Ts[TS(aC, 64 + ((i - 16) & 63), eC)];
        if (r & 1) { s1 += add; rg[r] = s1 * 0.125f; }
        else       { s0 += add; rg[r] = s0 * 0.125f; }
      }
    }
    __syncthreads();
#pragma unroll
    for (int r = 0; r < 16; ++r) Ts[TS(aC, qC * 16 + r, eC)] = rg[r];
    __syncthreads();
    // L1: bands 0,3 -> global (in place over X1)
    float* zp = X1 + X1_IDX(a0 + aC, u, 0, eC);
#pragma unroll
    for (int r = 0; r < 16; ++r) {
      const int i = qC * 16 + r, i2 = (i - 1) & 63;
      zp[i * 16] = 0.5f * (Ts[TS(aC, i, eC)] + Ts[TS(aC, 192 + i, eC)]
                         + Ts[TS(aC, i2, eC)] - Ts[TS(aC, 192 + i2, eC)]);
    }
  }
}

// ---------------- K5: axis-1 iSWT + bias skip -> out ----------------
// block 256 = q(4) x jl(4) x e(16); grid (32 a, 16 jc).
__global__ __launch_bounds__(256, 2) void k_iswt1(const float* __restrict__ Z1,
                                                  const float* __restrict__ x,
                                                  const float* __restrict__ bias,
                                                  float* __restrict__ out) {
  __shared__ float A[64 * 64], Bb[64 * 64], D[64 * 64], xs[64 * 64];  // 64 KB
  const int t = threadIdx.x;
  const int q = t >> 6, c = t & 63, jl = c >> 4, e = c & 15;
  const int a = blockIdx.x, j = blockIdx.y * 4 + jl;
  float4 bregs[4];
#pragma unroll
  for (int dq = 0; dq < 4; ++dq) bregs[dq] = *(const float4*)&bias[e * 16 + dq * 4];
  const float* Zp = Z1 + (size_t)a * 262144 + (size_t)j * 16 + e;  // + u*1024
#pragma unroll
  for (int r = 0; r < 16; ++r) {
    const int i = q * 16 + r;
    A[i * 64 + c] = Zp[(size_t)i * 1024];
    D[i * 64 + c] = Zp[(size_t)(64 + i) * 1024];
    xs[i * 64 + c] = x[((size_t)a * 4096 + (size_t)i * 64 + j) * 16 + e];
  }
  __syncthreads();
  float rg[16];
  // L6 -> Bb ; stage cD5 -> D
#pragma unroll
  for (int r = 0; r < 16; ++r) {
    const int i = q * 16 + r, i2 = (i - 32) & 63;
    rg[r] = 0.5f * (A[i * 64 + c] + D[i * 64 + c] + A[i2 * 64 + c] - D[i2 * 64 + c]);
  }
  __syncthreads();
#pragma unroll
  for (int r = 0; r < 16; ++r) {
    const int i = q * 16 + r;
    Bb[i * 64 + c] = rg[r];
    D[i * 64 + c] = Zp[(size_t)(128 + i) * 1024];
  }
  __syncthreads();
  // L5 -> A ; stage cD1 -> D
#pragma unroll
  for (int r = 0; r < 16; ++r) {
    const int i = q * 16 + r, i2 = (i - 16) & 63;
    rg[r] = 0.5f * (Bb[i * 64 + c] + D[i * 64 + c] + Bb[i2 * 64 + c] - D[i2 * 64 + c]);
  }
  __syncthreads();
#pragma unroll
  for (int r = 0; r < 16; ++r) {
    const int i = q * 16 + r;
    A[i * 64 + c] = rg[r];
    D[i * 64 + c] = Zp[(size_t)(192 + i) * 1024];
  }
  __syncthreads();
  // L4*L3*L2 composed, incremental sliding sum -> Bb
  {
    float s0 = 0.f, s1 = 0.f;
#pragma unroll
    for (int k = 0; k < 8; ++k) s0 += A[(((q * 16) - 2 * k) & 63) * 64 + c];
#pragma unroll
    for (int k = 0; k < 8; ++k) s1 += A[(((q * 16 + 1) - 2 * k) & 63) * 64 + c];
    rg[0] = s0 * 0.125f; rg[1] = s1 * 0.125f;
#pragma unroll
    for (int r = 2; r < 16; ++r) {
      const int i = q * 16 + r;
      const float add = A[i * 64 + c] - A[((i - 16) & 63) * 64 + c];
      if (r & 1) { s1 += add; rg[r] = s1 * 0.125f; }
      else       { s0 += add; rg[r] = s0 * 0.125f; }
    }
  }
  __syncthreads();
#pragma unroll
  for (int r = 0; r < 16; ++r) Bb[(q * 16 + r) * 64 + c] = rg[r];
  __syncthreads();
  // L1 + bias skip -> out
#pragma unroll
  for (int r = 0; r < 16; ++r) {
    const int i = q * 16 + r, i2 = (i - 1) & 63;
    const float v = 0.5f * (Bb[i * 64 + c] + D[i * 64 + c] + Bb[i2 * 64 + c] - D[i2 * 64 + c]);
    const float4 x0 = *(const float4*)&xs[i * 64 + jl * 16 + 0];
    const float4 x1 = *(const float4*)&xs[i * 64 + jl * 16 + 4];
    const float4 x2 = *(const float4*)&xs[i * 64 + jl * 16 + 8];
    const float4 x3 = *(const float4*)&xs[i * 64 + jl * 16 + 12];
    float s = x0.x * bregs[0].x + x0.y * bregs[0].y + x0.z * bregs[0].z + x0.w * bregs[0].w
            + x1.x * bregs[1].x + x1.y * bregs[1].y + x1.z * bregs[1].z + x1.w * bregs[1].w
            + x2.x * bregs[2].x + x2.y * bregs[2].y + x2.z * bregs[2].z + x2.w * bregs[2].w
            + x3.x * bregs[3].x + x3.y * bregs[3].y + x3.z * bregs[3].z + x3.w * bregs[3].w;
    out[((size_t)a * 4096 + (size_t)i * 64 + j) * 16 + e] = v + s;
  }
}

extern "C" void kernel_launch(void* const* d_in, const int* in_sizes, int n_in,
                              void* d_out, int out_size, void* d_ws, size_t ws_size,
                              hipStream_t stream) {
  const float* x = (const float*)d_in[0];
  const float* W = (const float*)d_in[1];
  const float* bias = (const float*)d_in[2];
  float* out = (float*)d_out;
  float* X1 = (float*)d_ws;  // 32 MB; both X1 and Z1 (fused stage is in place)

  k_swt1<<<dim3(32, 4), 256, 0, stream>>>(x, X1);
  k_fused<<<dim3(1024), 512, 0, stream>>>(X1, W);
  k_iswt1<<<dim3(32, 16), 256, 0, stream>>>(X1, x, bias, out);
}